// Round 3
// baseline (1421.782 us; speedup 1.0000x reference)
//
#include <hip/hip_runtime.h>
#include <math.h>

// MySimpleRNN on MI355X — split-N paired-block fp16 hi/lo MFMA.
// h = tanh(x_t@wx + b + h@wh), 64 steps, B=4096, NF=128, NH=512.
//
// Round-2 analysis: per-CU L1 weight-stream floor (1.31 MB/step @ 64B/clk =
// 8.5 us/step) reached 67% utilization; occupancy capped at 16 waves/CU.
// This round: SPLIT-N PAIRING. 256 blocks (1/CU), each block owns 32 batch
// rows x 256 output cols (half of NH). Per-CU weight stream halves to
// 640KB/step (floor 4.2us). Partner blocks (bid ^ 128, same XCD under
// round-robin %8) exchange their h-halves through L2 each step, published in
// MFMA-A-fragment-linear layout (lane-linear -> conflict-free ds_read and
// coalesced exchange). Sync latency hidden behind x-proj + own-half
// recurrence. Grid 256 = #CUs -> all blocks co-resident -> spin is safe.
// t=0 skips recurrence (h=0). Flags zeroed by prep each launch.
// Fallback to the round-2 kernel if ws_size < 18MB.
//
// mfma_f32_16x16x32_f16 layouts (verified learn_hip m89/m91/m120):
//   A: lane holds A[m=lane&15][k=(lane>>4)*8+j], j=0..7
//   B: lane holds B[k=(lane>>4)*8+j][n=lane&15]
//   C/D: reg r holds C[row=(lane>>4)*4+r][col=lane&15]

#define T_STEPS 64
#define NFD     128
#define NHD     512
#define THREADS 1024
#define LDX     (NFD + 8)    // x row stride in halfs (272 B)

typedef _Float16 half8 __attribute__((ext_vector_type(8)));
typedef _Float16 half4v __attribute__((ext_vector_type(4)));
typedef _Float16 half2v __attribute__((ext_vector_type(2)));
typedef float float4v __attribute__((ext_vector_type(4)));

// ws layout (bytes)
#define OFF_WHH   0u
#define OFF_WHL   (512u<<10)
#define OFF_WXH   (1024u<<10)
#define OFF_WXL   (1152u<<10)
#define OFF_FLAGS (1280u<<10)
#define OFF_XH    (2048u<<10)
#define OFF_XL    (10240u<<10)
#define WS_NEED   (18432u<<10)

// branch-free tanh: clamp +-9, (e-1)/(e+1), e = 2^(2x*log2e)
__device__ __forceinline__ float fast_tanh(float v) {
    float xc = fminf(fmaxf(v, -9.0f), 9.0f);
    float e  = __builtin_amdgcn_exp2f(xc * 2.8853900817779268f);
    return (e - 1.0f) * __builtin_amdgcn_rcpf(e + 1.0f);
}

// =====================  PAIRED-BLOCK PATH  =====================

// prep: split wh/wx into fp16 hi/lo, pack B-fragment-linear, per col-half.
// whp: half8 frag F = ((c*16 + g)*16 + ct)*64 + l, elem j <-
//      wh[(g*32 + (l>>4)*8 + j)*512 + c*256 + ct*16 + (l&15)]   (g = k-block 0..15)
// wxp: F = ((c*4 + kb)*16 + ct)*64 + l, same with wx, kb 0..3
// also zeroes the pair flags.
__global__ __launch_bounds__(256) void rnn_prep(
    const float* __restrict__ wh, const float* __restrict__ wx,
    _Float16* __restrict__ whp_hi, _Float16* __restrict__ whp_lo,
    _Float16* __restrict__ wxp_hi, _Float16* __restrict__ wxp_lo,
    unsigned int* __restrict__ flags)
{
    int idx = blockIdx.x * 256 + threadIdx.x;   // 0..262143
    {
        int j  = idx & 7;
        int l  = (idx >> 3) & 63;
        int ct = (idx >> 9) & 15;
        int g  = (idx >> 13) & 15;
        int c  = (idx >> 17) & 1;
        int k  = g * 32 + (l >> 4) * 8 + j;
        int n  = c * 256 + ct * 16 + (l & 15);
        float v = wh[k * NHD + n];
        _Float16 hi = (_Float16)v;
        whp_hi[idx] = hi;
        whp_lo[idx] = (_Float16)(v - (float)hi);
    }
    if (idx < 65536) {
        int j  = idx & 7;
        int l  = (idx >> 3) & 63;
        int ct = (idx >> 9) & 15;
        int kb = (idx >> 13) & 3;
        int c  = (idx >> 15) & 1;
        int k  = kb * 32 + (l >> 4) * 8 + j;
        int n  = c * 256 + ct * 16 + (l & 15);
        float v = wx[k * NHD + n];
        _Float16 hi = (_Float16)v;
        wxp_hi[idx] = hi;
        wxp_lo[idx] = (_Float16)(v - (float)hi);
    }
    if (idx < 1024) flags[idx] = 0u;
}

__global__ __launch_bounds__(THREADS, 4) void rnn_mfma(
    const float* __restrict__ x,
    const float* __restrict__ bias,
    const _Float16* __restrict__ whp_hi, const _Float16* __restrict__ whp_lo,
    const _Float16* __restrict__ wxp_hi, const _Float16* __restrict__ wxp_lo,
    _Float16* __restrict__ xchg_hi, _Float16* __restrict__ xchg_lo,
    unsigned int* __restrict__ flags,
    float* __restrict__ out)
{
    // fragment buffer: [rb(2)][kbl(8)][lane(64)][j(8)] halfs — time-shared:
    // phase (d) reads own h-frags (written by prev epilogue), phase (e)
    // overwrites with partner frags, phase (f) reads them, barrier, epilogue
    // rewrites own. Lane-linear 16B/lane -> conflict-free ds_read_b128.
    __shared__ _Float16 s_fh[8192];          // 16 KB
    __shared__ _Float16 s_fl[8192];          // 16 KB
    __shared__ _Float16 s_xh[32 * LDX];      // 8.5 KB
    __shared__ _Float16 s_xl[32 * LDX];      // 8.5 KB   -> ~49 KB total

    const int tid  = (int)threadIdx.x;
    const int lane = tid & 63;
    const int w    = tid >> 6;        // wave 0..15 = col-tile (16 cols)
    const int m    = lane & 15;
    const int quad = lane >> 4;

    const int nrt = (int)gridDim.x >> 1;             // 128
    const int c   = ((int)blockIdx.x >= nrt) ? 1 : 0;
    const int rt  = (int)blockIdx.x - c * nrt;       // row-tile 0..127
    const int row0 = rt * 32;

    // epilogue fragment coordinates for this thread
    const int kblS = w >> 1;                          // local k-block this wave's cols land in
    const int qqS  = ((w & 1) * 2 + (m >> 3)) & 3;    // A-quad
    const int jS   = m & 7;

    // bias for this lane's col tile
    const float bv = bias[c * 256 + w * 16 + m];

    // x prefetch: 1024 threads cover 32 rows x 128 floats, 4 floats each
    const int xrow = tid >> 5;          // 0..31
    const int xcol = (tid & 31) * 4;    // 0..124
    const float* xptr = x + (size_t)(row0 + xrow) * (T_STEPS * NFD) + xcol;
    float4v px = *(const float4v*)xptr;

    // wave-uniform-ish weight fragment pointers (half8 units, +lane folded in)
    const half8* wxB_h = (const half8*)wxp_hi + (((size_t)c * 4) * 16 + w) * 64 + lane;
    const half8* wxB_l = (const half8*)wxp_lo + (((size_t)c * 4) * 16 + w) * 64 + lane;
    const half8* whB_h = (const half8*)whp_hi + (((size_t)c * 16) * 16 + w) * 64 + lane;
    const half8* whB_l = (const half8*)whp_lo + (((size_t)c * 16) * 16 + w) * 64 + lane;
    const int gOwn = c * 8;          // own k-blocks: gOwn..gOwn+7
    const int gPrt = (1 - c) * 8;    // partner k-blocks

    // flag pointers
    unsigned int* flagMe = flags + (rt * 2 + c) * 2;
    unsigned int* flagPr = flags + (rt * 2 + (c ^ 1)) * 2;

    for (int t = 0; t < T_STEPS; ++t) {
        // (a) stage x(t): fp32 -> hi/lo fp16
        {
            half4v vh, vl;
            float xs[4] = {px[0], px[1], px[2], px[3]};
            #pragma unroll
            for (int j = 0; j < 4; ++j) {
                _Float16 hi = (_Float16)xs[j];
                vh[j] = hi;
                vl[j] = (_Float16)(xs[j] - (float)hi);
            }
            *(half4v*)&s_xh[xrow * LDX + xcol] = vh;
            *(half4v*)&s_xl[xrow * LDX + xcol] = vl;
        }
        __syncthreads();   // (1) x staged + prev-epilogue own-frags visible

        if (t + 1 < T_STEPS) px = *(const float4v*)(xptr + (t + 1) * NFD);

        float4v acc[2];
        #pragma unroll
        for (int rb = 0; rb < 2; ++rb) {
            acc[rb][0] = bv; acc[rb][1] = bv; acc[rb][2] = bv; acc[rb][3] = bv;
        }

        // (c) input projection: K=128 -> 4 k-blocks
        #pragma unroll
        for (int kb = 0; kb < 4; ++kb) {
            half8 bh = wxB_h[(size_t)kb * 1024];
            half8 bl = wxB_l[(size_t)kb * 1024];
            #pragma unroll
            for (int rb = 0; rb < 2; ++rb) {
                half8 ah = *(const half8*)&s_xh[(rb * 16 + m) * LDX + kb * 32 + quad * 8];
                half8 al = *(const half8*)&s_xl[(rb * 16 + m) * LDX + kb * 32 + quad * 8];
                acc[rb] = __builtin_amdgcn_mfma_f32_16x16x32_f16(ah, bh, acc[rb], 0, 0, 0);
                acc[rb] = __builtin_amdgcn_mfma_f32_16x16x32_f16(al, bh, acc[rb], 0, 0, 0);
                acc[rb] = __builtin_amdgcn_mfma_f32_16x16x32_f16(ah, bl, acc[rb], 0, 0, 0);
            }
        }

        if (t > 0) {
            // (d) recurrence, own half (h frags written by our prev epilogue)
            #pragma unroll 4
            for (int kbl = 0; kbl < 8; ++kbl) {
                half8 bh = whB_h[(size_t)(gOwn + kbl) * 1024];
                half8 bl = whB_l[(size_t)(gOwn + kbl) * 1024];
                #pragma unroll
                for (int rb = 0; rb < 2; ++rb) {
                    half8 ah = *(const half8*)&s_fh[((rb * 8 + kbl) * 64 + lane) * 8];
                    half8 al = *(const half8*)&s_fl[((rb * 8 + kbl) * 64 + lane) * 8];
                    acc[rb] = __builtin_amdgcn_mfma_f32_16x16x32_f16(ah, bh, acc[rb], 0, 0, 0);
                    acc[rb] = __builtin_amdgcn_mfma_f32_16x16x32_f16(al, bh, acc[rb], 0, 0, 0);
                    acc[rb] = __builtin_amdgcn_mfma_f32_16x16x32_f16(ah, bl, acc[rb], 0, 0, 0);
                }
            }

            // (2) wait for partner's h(t) publication (parity (t-1)&1, value >= t)
            if (tid == 0) {
                unsigned int* fp = flagPr + ((t - 1) & 1);
                while (__hip_atomic_load(fp, __ATOMIC_RELAXED, __HIP_MEMORY_SCOPE_AGENT) < (unsigned int)t) {}
                (void)__hip_atomic_load(fp, __ATOMIC_ACQUIRE, __HIP_MEMORY_SCOPE_AGENT);
            }
            __syncthreads();

            // (e) stage partner frags (32 KB) global -> LDS, 2 chunks/wave
            {
                size_t slotR = ((size_t)((t - 1) & 1) * (nrt * 2) + rt * 2 + (c ^ 1)) * 1024; // half8 units
                #pragma unroll
                for (int i = 0; i < 2; ++i) {
                    int cid  = w * 2 + i;          // 0..31
                    int comp = cid >> 4;           // 0=hi, 1=lo
                    int rbk  = cid & 15;           // rb*8 + kbl
                    const half8* src = (const half8*)(comp ? xchg_lo : xchg_hi) + slotR + rbk * 64 + lane;
                    half8 v = *src;
                    _Float16* dst = (comp ? s_fl : s_fh) + ((rbk * 64 + lane) * 8);
                    *(half8*)dst = v;
                }
            }
            __syncthreads();   // (3) partner frags staged

            // (f) recurrence, partner half
            #pragma unroll 4
            for (int kbl = 0; kbl < 8; ++kbl) {
                half8 bh = whB_h[(size_t)(gPrt + kbl) * 1024];
                half8 bl = whB_l[(size_t)(gPrt + kbl) * 1024];
                #pragma unroll
                for (int rb = 0; rb < 2; ++rb) {
                    half8 ah = *(const half8*)&s_fh[((rb * 8 + kbl) * 64 + lane) * 8];
                    half8 al = *(const half8*)&s_fl[((rb * 8 + kbl) * 64 + lane) * 8];
                    acc[rb] = __builtin_amdgcn_mfma_f32_16x16x32_f16(ah, bh, acc[rb], 0, 0, 0);
                    acc[rb] = __builtin_amdgcn_mfma_f32_16x16x32_f16(al, bh, acc[rb], 0, 0, 0);
                    acc[rb] = __builtin_amdgcn_mfma_f32_16x16x32_f16(ah, bl, acc[rb], 0, 0, 0);
                }
            }
            __syncthreads();   // (3.5) all partner-frag reads done before epilogue rewrites s_f*
        }

        // (g) epilogue
        if (t == T_STEPS - 1) {
            #pragma unroll
            for (int rb = 0; rb < 2; ++rb)
                #pragma unroll
                for (int r = 0; r < 4; ++r)
                    out[(size_t)(row0 + rb * 16 + quad * 4 + r) * NHD + c * 256 + w * 16 + m] =
                        fast_tanh(acc[rb][r]);
        } else {
            size_t slotW = ((size_t)(t & 1) * (nrt * 2) + rt * 2 + c) * 8192; // halfs
            #pragma unroll
            for (int rb = 0; rb < 2; ++rb) {
                #pragma unroll
                for (int r = 0; r < 4; ++r) {
                    float v = fast_tanh(acc[rb][r]);
                    _Float16 hi = (_Float16)v;
                    _Float16 lo = (_Float16)(v - (float)hi);
                    int fo = ((rb * 8 + kblS) * 64 + (qqS * 16 + quad * 4 + r)) * 8 + jS;
                    s_fh[fo] = hi;
                    s_fl[fo] = lo;
                    xchg_hi[slotW + fo] = hi;
                    xchg_lo[slotW + fo] = lo;
                }
            }
            __syncthreads();   // (4) all LDS + exchange writes done
            if (tid == 0) {
                __hip_atomic_store(flagMe + (t & 1), (unsigned int)(t + 1),
                                   __ATOMIC_RELEASE, __HIP_MEMORY_SCOPE_AGENT);
            }
        }
    }
}

// =====================  FALLBACK PATH (round-2 kernel, proven)  =====================

#define LDHF (NHD + 8)

__global__ __launch_bounds__(256) void rnn_prep_fb(
    const float* __restrict__ wh, const float* __restrict__ wx,
    _Float16* __restrict__ whp_hi, _Float16* __restrict__ whp_lo,
    _Float16* __restrict__ wxp_hi, _Float16* __restrict__ wxp_lo)
{
    int idx = blockIdx.x * 256 + threadIdx.x;
    {
        int j  = idx & 7;
        int l  = (idx >> 3) & 63;
        int nt = (idx >> 9) & 3;
        int kb = (idx >> 11) & 15;
        int w  = idx >> 15;
        int k  = kb * 32 + (l >> 4) * 8 + j;
        int n  = w * 64 + nt * 16 + (l & 15);
        float v = wh[k * NHD + n];
        _Float16 hi = (_Float16)v;
        whp_hi[idx] = hi;
        whp_lo[idx] = (_Float16)(v - (float)hi);
    }
    if (idx < 65536) {
        int j  = idx & 7;
        int l  = (idx >> 3) & 63;
        int nt = (idx >> 9) & 3;
        int kb = (idx >> 11) & 3;
        int w  = idx >> 13;
        int k  = kb * 32 + (l >> 4) * 8 + j;
        int n  = w * 64 + nt * 16 + (l & 15);
        float v = wx[k * NHD + n];
        _Float16 hi = (_Float16)v;
        wxp_hi[idx] = hi;
        wxp_lo[idx] = (_Float16)(v - (float)hi);
    }
}

__global__ __launch_bounds__(1024, 4) void rnn_mfma_fb(
    const float* __restrict__ x,
    const float* __restrict__ bias,
    const _Float16* __restrict__ whp_hi, const _Float16* __restrict__ whp_lo,
    const _Float16* __restrict__ wxp_hi, const _Float16* __restrict__ wxp_lo,
    float* __restrict__ out)
{
    __shared__ _Float16 sh_hhi[16 * LDHF];
    __shared__ _Float16 sh_hlo[16 * LDHF];
    __shared__ _Float16 sh_xhi[16 * LDX];
    __shared__ _Float16 sh_xlo[16 * LDX];

    const int tid  = (int)threadIdx.x;
    const int lane = tid & 63;
    const int w    = tid >> 6;
    const int m    = lane & 15;
    const int quad = lane >> 4;
    const int row0 = (int)blockIdx.x * 16;

    for (int i = tid; i < 16 * LDHF; i += 1024) {
        sh_hhi[i] = (_Float16)0.f;
        sh_hlo[i] = (_Float16)0.f;
    }

    float bv[2];
    #pragma unroll
    for (int nt = 0; nt < 2; ++nt) bv[nt] = bias[w * 32 + nt * 16 + m];

    const int xrow = tid >> 6;
    const int xcol = (tid & 63) * 2;
    const float* xptr = x + (size_t)(row0 + xrow) * (T_STEPS * NFD) + xcol;
    float2 px = *(const float2*)xptr;

    const half8* wxh = (const half8*)wxp_hi + (size_t)(w >> 1) * 1024 + (w & 1) * 128;
    const half8* wxl = (const half8*)wxp_lo + (size_t)(w >> 1) * 1024 + (w & 1) * 128;
    const half8* whh = (const half8*)whp_hi + (size_t)(w >> 1) * 4096 + (w & 1) * 128;
    const half8* whl = (const half8*)whp_lo + (size_t)(w >> 1) * 4096 + (w & 1) * 128;

    for (int t = 0; t < T_STEPS; ++t) {
        {
            half2v vh, vl;
            float xs[2] = {px.x, px.y};
            #pragma unroll
            for (int j = 0; j < 2; ++j) {
                _Float16 hi = (_Float16)xs[j];
                vh[j] = hi;
                vl[j] = (_Float16)(xs[j] - (float)hi);
            }
            *(half2v*)&sh_xhi[xrow * LDX + xcol] = vh;
            *(half2v*)&sh_xlo[xrow * LDX + xcol] = vl;
        }
        __syncthreads();

        if (t + 1 < T_STEPS) px = *(const float2*)(xptr + (t + 1) * NFD);

        float4v acc[2];
        #pragma unroll
        for (int nt = 0; nt < 2; ++nt) {
            acc[nt][0] = bv[nt]; acc[nt][1] = bv[nt];
            acc[nt][2] = bv[nt]; acc[nt][3] = bv[nt];
        }

        #pragma unroll
        for (int kb = 0; kb < 4; ++kb) {
            half8 ah = *(const half8*)&sh_xhi[m * LDX + kb * 32 + quad * 8];
            half8 al = *(const half8*)&sh_xlo[m * LDX + kb * 32 + quad * 8];
            half8 bh0 = wxh[kb * 256 + lane];
            half8 bh1 = wxh[kb * 256 + 64 + lane];
            half8 bl0 = wxl[kb * 256 + lane];
            half8 bl1 = wxl[kb * 256 + 64 + lane];
            acc[0] = __builtin_amdgcn_mfma_f32_16x16x32_f16(ah, bh0, acc[0], 0, 0, 0);
            acc[0] = __builtin_amdgcn_mfma_f32_16x16x32_f16(al, bh0, acc[0], 0, 0, 0);
            acc[0] = __builtin_amdgcn_mfma_f32_16x16x32_f16(ah, bl0, acc[0], 0, 0, 0);
            acc[1] = __builtin_amdgcn_mfma_f32_16x16x32_f16(ah, bh1, acc[1], 0, 0, 0);
            acc[1] = __builtin_amdgcn_mfma_f32_16x16x32_f16(al, bh1, acc[1], 0, 0, 0);
            acc[1] = __builtin_amdgcn_mfma_f32_16x16x32_f16(ah, bl1, acc[1], 0, 0, 0);
        }

        #pragma unroll 4
        for (int kb = 0; kb < 16; ++kb) {
            half8 ah = *(const half8*)&sh_hhi[m * LDHF + kb * 32 + quad * 8];
            half8 al = *(const half8*)&sh_hlo[m * LDHF + kb * 32 + quad * 8];
            half8 bh0 = whh[kb * 256 + lane];
            half8 bh1 = whh[kb * 256 + 64 + lane];
            half8 bl0 = whl[kb * 256 + lane];
            half8 bl1 = whl[kb * 256 + 64 + lane];
            acc[0] = __builtin_amdgcn_mfma_f32_16x16x32_f16(ah, bh0, acc[0], 0, 0, 0);
            acc[0] = __builtin_amdgcn_mfma_f32_16x16x32_f16(al, bh0, acc[0], 0, 0, 0);
            acc[0] = __builtin_amdgcn_mfma_f32_16x16x32_f16(ah, bl0, acc[0], 0, 0, 0);
            acc[1] = __builtin_amdgcn_mfma_f32_16x16x32_f16(ah, bh1, acc[1], 0, 0, 0);
            acc[1] = __builtin_amdgcn_mfma_f32_16x16x32_f16(al, bh1, acc[1], 0, 0, 0);
            acc[1] = __builtin_amdgcn_mfma_f32_16x16x32_f16(ah, bl1, acc[1], 0, 0, 0);
        }

        __syncthreads();

        if (t == T_STEPS - 1) {
            #pragma unroll
            for (int nt = 0; nt < 2; ++nt)
                #pragma unroll
                for (int r = 0; r < 4; ++r)
                    out[(size_t)(row0 + quad * 4 + r) * NHD + w * 32 + nt * 16 + m] =
                        fast_tanh(acc[nt][r]);
        } else {
            #pragma unroll
            for (int nt = 0; nt < 2; ++nt) {
                #pragma unroll
                for (int r = 0; r < 4; ++r) {
                    float v = fast_tanh(acc[nt][r]);
                    _Float16 hi = (_Float16)v;
                    int off = (quad * 4 + r) * LDHF + w * 32 + nt * 16 + m;
                    sh_hhi[off] = hi;
                    sh_hlo[off] = (_Float16)(v - (float)hi);
                }
            }
        }
    }
}

// =====================  LAUNCH  =====================

extern "C" void kernel_launch(void* const* d_in, const int* in_sizes, int n_in,
                              void* d_out, int out_size, void* d_ws, size_t ws_size,
                              hipStream_t stream) {
    const float* x    = (const float*)d_in[0];  // [B, 64, 128]
    const float* wx   = (const float*)d_in[1];  // [128, 512]
    const float* wh   = (const float*)d_in[2];  // [512, 512]
    const float* bias = (const float*)d_in[3];  // [512]
    float* out = (float*)d_out;                 // [B, 512]

    char* ws = (char*)d_ws;
    _Float16* whp_hi = (_Float16*)(ws + OFF_WHH);
    _Float16* whp_lo = (_Float16*)(ws + OFF_WHL);
    _Float16* wxp_hi = (_Float16*)(ws + OFF_WXH);
    _Float16* wxp_lo = (_Float16*)(ws + OFF_WXL);

    const int B = in_sizes[0] / (T_STEPS * NFD);   // 4096

    if (ws_size >= (size_t)WS_NEED && (B % 32) == 0 && ((B / 32) % 8) == 0) {
        unsigned int* flags = (unsigned int*)(ws + OFF_FLAGS);
        _Float16* xchg_hi   = (_Float16*)(ws + OFF_XH);
        _Float16* xchg_lo   = (_Float16*)(ws + OFF_XL);
        rnn_prep<<<1024, 256, 0, stream>>>(wh, wx, whp_hi, whp_lo, wxp_hi, wxp_lo, flags);
        rnn_mfma<<<(B / 32) * 2, THREADS, 0, stream>>>(
            x, bias, whp_hi, whp_lo, wxp_hi, wxp_lo, xchg_hi, xchg_lo, flags, out);
    } else {
        rnn_prep_fb<<<1024, 256, 0, stream>>>(wh, wx, whp_hi, whp_lo, wxp_hi, wxp_lo);
        rnn_mfma_fb<<<B / 16, 1024, 0, stream>>>(x, bias, whp_hi, whp_lo, wxp_hi, wxp_lo, out);
    }
}